// Round 8
// baseline (341.554 us; speedup 1.0000x reference)
//
#include <hip/hip_runtime.h>
#include <hip/hip_bf16.h>
#include <stdint.h>

#define DIM    1024
#define SEQ    2048
#define NB     2
#define NH     16
#define HD     64
#define NROWS  (NB*SEQ)   // 4096

typedef unsigned short u16;
typedef __attribute__((ext_vector_type(8))) short bf16x8;
typedef __attribute__((ext_vector_type(4))) short bf16x4;
typedef __attribute__((ext_vector_type(4))) float f32x4;
typedef __attribute__((ext_vector_type(4))) unsigned short u16x4;

#define NEG_INF (-__builtin_inff())

// float -> bf16 with round-to-nearest-even (cold paths)
__device__ __forceinline__ u16 f2bf(float f) {
    union { float f; uint32_t u; } x; x.f = f;
    uint32_t r = x.u + 0x7FFFu + ((x.u >> 16) & 1u);
    return (u16)(r >> 16);
}

// packed f32x2 -> bf16x2 (RNE on gfx950) — hot-path conversion
__device__ __forceinline__ uint32_t cvtpk(float a, float b) {
    uint32_t r;
    asm volatile("v_cvt_pk_bf16_f32 %0, %1, %2" : "=v"(r) : "v"(a), "v"(b));
    return r;
}

// async global->LDS, 16B per lane. LDS dest is wave-uniform base + lane*16.
__device__ __forceinline__ void gload_lds16(const void* g, void* l) {
    __builtin_amdgcn_global_load_lds(
        (const __attribute__((address_space(1))) void*)g,
        (__attribute__((address_space(3))) void*)l, 16, 0, 0);
}

// ---------------------------------------------------------------------------
// x (fp32 [4096][1024]) -> bf16. 4 elems/thread, exact cover.
// ---------------------------------------------------------------------------
__global__ __launch_bounds__(256)
void cvt_x(const float* __restrict__ in, u16* __restrict__ out)
{
    size_t i = (size_t)blockIdx.x * 256 + threadIdx.x;   // < 1048576
    float4 f = *(const float4*)&in[i * 4];
    u16x4 o = { f2bf(f.x), f2bf(f.y), f2bf(f.z), f2bf(f.w) };
    *(u16x4*)&out[i * 4] = o;
}

// ---------------------------------------------------------------------------
// W (fp32 [K=1024][N=1024]) -> Wt (bf16 [N][K]) — LDS-tiled 64x64 transpose.
// ---------------------------------------------------------------------------
__global__ __launch_bounds__(256)
void cvt_w(const float* __restrict__ Wq, const float* __restrict__ Wk,
           const float* __restrict__ Wv, const float* __restrict__ Wo,
           u16* __restrict__ Wqt, u16* __restrict__ Wkt,
           u16* __restrict__ Wvt, u16* __restrict__ Wot)
{
    __shared__ u16 Ws[64][68];
    const int z = blockIdx.z;
    const float* W = z == 0 ? Wq : z == 1 ? Wk : z == 2 ? Wv : Wo;
    u16* Wt        = z == 0 ? Wqt : z == 1 ? Wkt : z == 2 ? Wvt : Wot;
    const int k0 = blockIdx.x * 64;
    const int n0 = blockIdx.y * 64;
    const int tid = threadIdx.x;

    #pragma unroll
    for (int it = 0; it < 4; ++it) {
        int idx = tid + it * 256;
        int r = idx >> 4, cq = idx & 15;
        float4 f = *(const float4*)&W[(size_t)(k0 + r) * DIM + n0 + cq * 4];
        u16x4 o = { f2bf(f.x), f2bf(f.y), f2bf(f.z), f2bf(f.w) };
        *(u16x4*)&Ws[r][cq * 4] = o;
    }
    __syncthreads();
    #pragma unroll
    for (int it = 0; it < 4; ++it) {
        int idx = tid + it * 256;
        int rr = idx >> 4, cq = idx & 15;
        u16x4 o = { Ws[cq*4+0][rr], Ws[cq*4+1][rr], Ws[cq*4+2][rr], Ws[cq*4+3][rr] };
        *(u16x4*)&Wt[(size_t)(n0 + rr) * DIM + k0 + cq * 4] = o;
    }
}

// ---------------------------------------------------------------------------
// V [bh][t][d] -> V^T [bh][d][t] — LDS-tiled 64x64 transpose (bf16).
// ---------------------------------------------------------------------------
__global__ __launch_bounds__(256)
void cvt_vt(const u16* __restrict__ vb, u16* __restrict__ vbt)
{
    __shared__ u16 T[64][65];
    const int tid = threadIdx.x;
    const int t0  = blockIdx.x * 64;
    const size_t hb = (size_t)blockIdx.y << 17;   // bh * SEQ * HD

    const int r  = tid >> 2;
    const int c0 = (tid & 3) * 16;
    const u16* src = vb + hb + ((size_t)(t0 + r) << 6) + c0;
    bf16x8 v0 = *(const bf16x8*)src;
    bf16x8 v1 = *(const bf16x8*)(src + 8);
    #pragma unroll
    for (int i = 0; i < 8; ++i) {
        T[r][c0 + i]     = (u16)v0[i];
        T[r][c0 + 8 + i] = (u16)v1[i];
    }
    __syncthreads();
    const int d = tid >> 2;
    u16 tmp[16];
    #pragma unroll
    for (int i = 0; i < 16; ++i) tmp[i] = T[c0 + i][d];
    u16* dst = vbt + hb + ((size_t)d << 11) + t0 + c0;
    *(bf16x8*)dst       = *(bf16x8*)&tmp[0];
    *(bf16x8*)(dst + 8) = *(bf16x8*)&tmp[8];
}

// ---------------------------------------------------------------------------
// bf16 MFMA GEMM: C[M,N] = A[M,K] @ Wt^T + bias.
// MODE 0: fused QKV; Q output pre-scaled by 0.125*log2(e) (exp2-domain SM).
// MODE 1: single GEMM, fp32 out.
// ---------------------------------------------------------------------------
template<int MODE>
__global__ __launch_bounds__(256)
void gemm_mfma(const u16* __restrict__ A,
               const u16* __restrict__ Wt0, const u16* __restrict__ Wt1,
               const u16* __restrict__ Wt2,
               const float* __restrict__ b0, const float* __restrict__ b1,
               const float* __restrict__ b2,
               void* __restrict__ o0, void* __restrict__ o1, void* __restrict__ o2)
{
    __shared__ __align__(16) uint8_t lds[32768];
    uint8_t* Asb = lds;            // 128 rows x 128B (64 bf16), swizzled
    uint8_t* Bsb = lds + 16384;

    const int tid  = threadIdx.x;
    const int wid  = tid >> 6, lane = tid & 63;
    const int lr   = lane & 15, lg = lane >> 4;
    const int wr   = wid >> 1, wc = wid & 1;

    const int r0 = blockIdx.x * 128;
    const int c0 = blockIdx.y * 128;

    const u16* Wt; const float* bias; u16* obf = nullptr; float* ofp = nullptr;
    int cw; float qscale = 1.0f;
    if (MODE == 0) {
        int sel = c0 >> 10;              // 0..2 -> Q,K,V (128 | 1024)
        cw  = c0 & 1023;
        Wt   = sel == 0 ? Wt0 : sel == 1 ? Wt1 : Wt2;
        bias = sel == 0 ? b0  : sel == 1 ? b1  : b2;
        obf  = (u16*)(sel == 0 ? o0 : sel == 1 ? o1 : o2);
        if (sel == 0) qscale = 0.125f * 1.44269504088896f;   // 1/sqrt(64)*log2e
    } else {
        cw = c0; Wt = Wt0; bias = b0; ofp = (float*)o0;
    }

    f32x4 acc[4][4] = {};

    for (int k0 = 0; k0 < DIM; k0 += 64) {
        __syncthreads();   // previous compute done before overwrite
        #pragma unroll
        for (int seg = 0; seg < 4; ++seg) {
            int o   = seg * 4096 + tid * 16;        // linear LDS byte offset
            int row = o >> 7;                       // /128B per row
            int sch = ((o >> 4) & 7) ^ (row & 7);   // inverse-swizzled src chunk
            gload_lds16((const uint8_t*)A  + ((size_t)(r0 + row) << 11) + (k0 << 1) + (sch << 4),
                        Asb + seg * 4096 + (wid << 10) + (lane << 4));
            gload_lds16((const uint8_t*)Wt + ((size_t)(cw + row) << 11) + (k0 << 1) + (sch << 4),
                        Bsb + seg * 4096 + (wid << 10) + (lane << 4));
        }
        __syncthreads();   // staging visible

        __builtin_amdgcn_s_setprio(1);
        #pragma unroll
        for (int kk = 0; kk < 2; ++kk) {
            bf16x8 a[4], b[4];
            #pragma unroll
            for (int i = 0; i < 4; ++i) {
                int ar = wr * 64 + i * 16 + lr;
                a[i] = *(const bf16x8*)(Asb + ar * 128 + ((((kk << 2) | lg) ^ (ar & 7)) << 4));
                int br = wc * 64 + i * 16 + lr;
                b[i] = *(const bf16x8*)(Bsb + br * 128 + ((((kk << 2) | lg) ^ (br & 7)) << 4));
            }
            #pragma unroll
            for (int i = 0; i < 4; ++i)
                #pragma unroll
                for (int j = 0; j < 4; ++j)
                    acc[i][j] = __builtin_amdgcn_mfma_f32_16x16x32_bf16(a[i], b[j], acc[i][j], 0, 0, 0);
        }
        __builtin_amdgcn_s_setprio(0);
    }

    // Epilogue. C/D layout: col = lane&15, row = (lane>>4)*4+reg.
    #pragma unroll
    for (int j = 0; j < 4; ++j) {
        int colw = wc * 64 + j * 16 + lr;          // 0..127 within tile
        float bv = bias[cw + colw];
        #pragma unroll
        for (int i = 0; i < 4; ++i) {
            #pragma unroll
            for (int r = 0; r < 4; ++r) {
                float val = (acc[i][j][r] + bv) * qscale;
                int row = r0 + wr * 64 + i * 16 + lg * 4 + r;
                if (MODE == 0) {
                    int col = cw + colw;           // 0..1023 within this W
                    int h = col >> 6, d = col & 63;
                    int bb = row >> 11, t = row & (SEQ - 1);
                    obf[((((size_t)bb * NH + h) * SEQ + t) << 6) + d] = f2bf(val);
                } else {
                    ofp[((size_t)row << 10) + c0 + colw] = val;
                }
            }
        }
    }
}

// ---------------------------------------------------------------------------
// Barrier-free flash attention: NO LDS, NO __syncthreads in the kv loop.
// Each wave independently reads K fragments (contiguous b128, natural
// [t][d] layout) and V^T fragments (b64 pairs from [d][t] layout) straight
// from global (L1/L2-resident: co-resident blocks share bh since qt is in
// the high bits of blockIdx). Swapped-QK^T in-register softmax (exp2
// domain, defer-max), P stays in-lane and pairs with V^T's kv slices.
//
// SPLIT=1: (bh,qt) split into 2 kv-chunks -> unnormalized partials + (m,l);
// combine kernel merges. SPLIT=0: single block per (bh,qt), direct store.
// ---------------------------------------------------------------------------
template<int SPLIT>
__global__ __launch_bounds__(256)
void attn_mfma(const u16* __restrict__ q, const u16* __restrict__ k,
               const u16* __restrict__ vt, u16* __restrict__ ctx,
               float* __restrict__ pO, float* __restrict__ pML)
{
    const int tid = threadIdx.x;
    const int wid = tid >> 6, lane = tid & 63;
    const int lr  = lane & 15, lg = lane >> 4;

    const int n = blockIdx.x;
    int bh, qt, k_lo, k_hi, pidx = 0;
    if (SPLIT) {
        // n = qt*64 + bh*2 + chunk  (qt in high bits -> co-resident share bh)
        qt = n >> 6; bh = (n >> 1) & 31;
        int chunk = n & 1;
        int T = qt + 1, hh = (T + 1) >> 1;
        k_lo = chunk ? hh : 0;
        k_hi = chunk ? T : hh;
        pidx = (((bh << 5) | qt) << 1) | chunk;
    } else {
        qt = n >> 5; bh = n & 31;
        k_lo = 0; k_hi = qt + 1;
    }

    const size_t hb = (size_t)bh << 17;     // bh * SEQ * HD
    const int q0 = qt * 64;

    // Q fragments: direct global->reg (row = q0 + wid*16 + lr)
    const u16* qrow = q + hb + ((size_t)(q0 + wid * 16 + lr) << 6);
    bf16x8 aQ0 = *(const bf16x8*)(qrow + lg * 8);
    bf16x8 aQ1 = *(const bf16x8*)(qrow + 32 + lg * 8);

    f32x4 acc[4] = {};
    float m_own = NEG_INF;   // running max (log2-domain) for q-row wid*16+lr
    float l_own = 0.f;

    for (int kt = k_lo; kt < k_hi; ++kt) {
        const u16* kb_t = k  + hb + ((size_t)kt << 12);   // K tile [64][64]
        const u16* vt_t = vt + hb + kt * 64;              // V^T cols kt*64..

        // S^T = K·Q : A = K fragment (direct global), B = Q fragment
        f32x4 s[4];
        __builtin_amdgcn_s_setprio(1);
        #pragma unroll
        for (int j = 0; j < 4; ++j) {
            const u16* krp = kb_t + ((j * 16 + lr) << 6);
            bf16x8 b0 = *(const bf16x8*)(krp + lg * 8);
            bf16x8 b1 = *(const bf16x8*)(krp + 32 + lg * 8);
            f32x4 z = {0.f, 0.f, 0.f, 0.f};
            z    = __builtin_amdgcn_mfma_f32_16x16x32_bf16(b0, aQ0, z, 0, 0, 0);
            s[j] = __builtin_amdgcn_mfma_f32_16x16x32_bf16(b1, aQ1, z, 0, 0, 0);
        }
        __builtin_amdgcn_s_setprio(0);

        // V^T fragment loads — issued NOW, consumed after softmax (latency
        // hides under ~60 VALU ops). vb0[ni] covers kv {lg*4..+3, 32+lg*4..+3}
        // of d = ni*16+lr; vb1 the +16/+48 slices — exactly pairing P0/P1.
        bf16x8 vb0[4], vb1[4];
        #pragma unroll
        for (int ni = 0; ni < 4; ++ni) {
            const u16* vr = vt_t + ((size_t)(ni * 16 + lr) << 11) + lg * 4;
            bf16x4 a0 = *(const bf16x4*)(vr);
            bf16x4 c0 = *(const bf16x4*)(vr + 16);
            bf16x4 a1 = *(const bf16x4*)(vr + 32);
            bf16x4 c1 = *(const bf16x4*)(vr + 48);
            vb0[ni] = bf16x8{a0[0],a0[1],a0[2],a0[3], a1[0],a1[1],a1[2],a1[3]};
            vb1[ni] = bf16x8{c0[0],c0[1],c0[2],c0[3], c1[0],c1[1],c1[2],c1[3]};
        }

        if (kt == qt) {                  // causal mask (tile-relative)
            #pragma unroll
            for (int j = 0; j < 4; ++j)
                #pragma unroll
                for (int r = 0; r < 4; ++r)
                    if (j * 16 + lg * 4 + r > wid * 16 + lr) s[j][r] = NEG_INF;
        }

        // softmax over this lane's 16 kv values (log2 domain)
        float rm = NEG_INF;
        #pragma unroll
        for (int j = 0; j < 4; ++j) {
            float a = fmaxf(fmaxf(s[j][0], s[j][1]), fmaxf(s[j][2], s[j][3]));
            rm = fmaxf(rm, a);
        }
        rm = fmaxf(rm, __shfl_xor(rm, 16));
        rm = fmaxf(rm, __shfl_xor(rm, 32));

        // defer-max: only rescale when the max actually grew (P <= 2^8)
        if (!__all(rm <= m_own + 8.f)) {
            float mnew = fmaxf(m_own, rm);
            float aown = exp2f(m_own - mnew);   // first tile: exp2(-inf)=0
            m_own = mnew;
            l_own *= aown;
            float ar[4];
            #pragma unroll
            for (int r = 0; r < 4; ++r) ar[r] = __shfl(aown, lg * 4 + r);
            #pragma unroll
            for (int ni = 0; ni < 4; ++ni)
                #pragma unroll
                for (int r = 0; r < 4; ++r)
                    acc[ni][r] *= ar[r];
        }

        float rs = 0.f;
        #pragma unroll
        for (int j = 0; j < 4; ++j)
            #pragma unroll
            for (int r = 0; r < 4; ++r) {
                float p = exp2f(s[j][r] - m_own);
                s[j][r] = p;
                rs += p;
            }
        rs += __shfl_xor(rs, 16);
        rs += __shfl_xor(rs, 32);
        l_own += rs;

        // P A-fragments via packed cvt: pa0 = {s0[0..3], s2[0..3]}, pa1 = {s1,s3}
        union { uint32_t u[4]; bf16x8 h; } P0, P1;
        P0.u[0] = cvtpk(s[0][0], s[0][1]); P0.u[1] = cvtpk(s[0][2], s[0][3]);
        P0.u[2] = cvtpk(s[2][0], s[2][1]); P0.u[3] = cvtpk(s[2][2], s[2][3]);
        P1.u[0] = cvtpk(s[1][0], s[1][1]); P1.u[1] = cvtpk(s[1][2], s[1][3]);
        P1.u[2] = cvtpk(s[3][0], s[3][1]); P1.u[3] = cvtpk(s[3][2], s[3][3]);

        // O += P @ V
        __builtin_amdgcn_s_setprio(1);
        #pragma unroll
        for (int ni = 0; ni < 4; ++ni) {
            acc[ni] = __builtin_amdgcn_mfma_f32_16x16x32_bf16(P0.h, vb0[ni], acc[ni], 0, 0, 0);
            acc[ni] = __builtin_amdgcn_mfma_f32_16x16x32_bf16(P1.h, vb1[ni], acc[ni], 0, 0, 0);
        }
        __builtin_amdgcn_s_setprio(0);
    }

    if (SPLIT) {
        // partial O (unnormalized fp32) + (m,l)
        float* Op = pO + (size_t)pidx * 4096;
        #pragma unroll
        for (int r = 0; r < 4; ++r) {
            int row = wid * 16 + lg * 4 + r;
            #pragma unroll
            for (int ni = 0; ni < 4; ++ni)
                Op[row * 64 + ni * 16 + lr] = acc[ni][r];
        }
        if (lg == 0) {   // lanes 0..15 hold rows wid*16+lr
            pML[pidx * 128 + wid * 16 + lr]      = m_own;
            pML[pidx * 128 + 64 + wid * 16 + lr] = l_own;
        }
    } else {
        float rinv = 1.f / l_own;
        float rl[4];
        #pragma unroll
        for (int r = 0; r < 4; ++r) rl[r] = __shfl(rinv, lg * 4 + r);
        const int b = bh >> 4, h = bh & 15;
        #pragma unroll
        for (int r = 0; r < 4; ++r) {
            int t = q0 + wid * 16 + lg * 4 + r;
            size_t base = (((size_t)b * SEQ + t) << 10) + (h << 6);
            #pragma unroll
            for (int ni = 0; ni < 4; ++ni)
                ctx[base + ni * 16 + lr] = f2bf(acc[ni][r] * rl[r]);
        }
    }
}

// ---------------------------------------------------------------------------
// Merge the 2 kv-chunk partials: O = (O0*2^(m0-m) + O1*2^(m1-m)) / l.
// One thread per (q-row, 16-d segment): 262144 threads.
// ---------------------------------------------------------------------------
__global__ __launch_bounds__(256)
void attn_combine(const float* __restrict__ pO, const float* __restrict__ pML,
                  u16* __restrict__ ctx)
{
    int gid  = blockIdx.x * 256 + threadIdx.x;   // < 262144
    int rg   = gid >> 2;                         // global q-row 0..65535
    int dseg = gid & 3;
    int bh = rg >> 11;
    int qt = (rg >> 6) & 31;
    int r  = rg & 63;
    int p0 = ((bh << 5) | qt) << 1;

    float m0 = pML[p0 * 128 + r],       l0 = pML[p0 * 128 + 64 + r];
    float m1 = pML[(p0 + 1) * 128 + r], l1 = pML[(p0 + 1) * 128 + 64 + r];
    float m  = fmaxf(m0, m1);
    float s0 = exp2f(m0 - m), s1 = exp2f(m1 - m);
    float rl = 1.f / (l0 * s0 + l1 * s1);

    const float* O0 = pO + (size_t)p0 * 4096 + r * 64 + dseg * 16;
    const float* O1 = O0 + 4096;

    int b = bh >> 4, h = bh & 15, t = qt * 64 + r;
    u16* dst = ctx + (((size_t)b * SEQ + t) << 10) + (h << 6) + dseg * 16;

    u16x4 o[4];
    #pragma unroll
    for (int i = 0; i < 4; ++i) {
        float4 a = *(const float4*)&O0[i * 4];
        float4 c = *(const float4*)&O1[i * 4];
        o[i].x = f2bf((a.x * s0 + c.x * s1) * rl);
        o[i].y = f2bf((a.y * s0 + c.y * s1) * rl);
        o[i].z = f2bf((a.z * s0 + c.z * s1) * rl);
        o[i].w = f2bf((a.w * s0 + c.w * s1) * rl);
    }
    *(u16x4*)(dst)      = o[0];
    *(u16x4*)(dst + 4)  = o[1];
    *(u16x4*)(dst + 8)  = o[2];
    *(u16x4*)(dst + 12) = o[3];
}

// ---------------------------------------------------------------------------
extern "C" void kernel_launch(void* const* d_in, const int* in_sizes, int n_in,
                              void* d_out, int out_size, void* d_ws, size_t ws_size,
                              hipStream_t stream)
{
    (void)in_sizes; (void)n_in; (void)out_size;
    const float* x  = (const float*)d_in[0];
    const float* Wq = (const float*)d_in[1];
    const float* bq = (const float*)d_in[2];
    const float* Wk = (const float*)d_in[3];
    const float* bk = (const float*)d_in[4];
    const float* Wv = (const float*)d_in[5];
    const float* bv = (const float*)d_in[6];
    const float* Wo = (const float*)d_in[7];
    const float* bo = (const float*)d_in[8];

    u16* ws = (u16*)d_ws;
    const size_t M1 = (size_t)1024 * 1024;     // 1M elems
    const size_t M4 = (size_t)NROWS * DIM;     // 4M elems
    u16* xb  = ws;                 // x as bf16; REUSED as V^T after gemm0
    u16* wqt = ws + M4;            // W^T bf16 [n][k]               (2 MB each)
    u16* wkt = wqt + M1;
    u16* wvt = wkt + M1;
    u16* wot = wvt + M1;
    u16* qb  = wot + M1;           // q/k/v bf16 [B,H,T,D]          (8 MB each)
    u16* kb  = qb + M4;
    u16* vb  = kb + M4;
    u16* cb  = vb + M4;            // ctx bf16 [B,T,C]              (8 MB)
    float* pO  = (float*)(cb + M4);            // 2048 x 4096 fp32  (33.5 MB)
    float* pML = pO + (size_t)2048 * 4096;     // 2048 x 128  fp32  (1 MB)

    const size_t need = (size_t)(cb + M4 - ws) * 2      // 48 MB in bytes
                      + (size_t)2048 * 4096 * 4 + (size_t)2048 * 128 * 4;
    const bool split = ws_size >= need;

    cvt_x<<<dim3(4096), dim3(256), 0, stream>>>(x, xb);
    cvt_w<<<dim3(16, 16, 4), dim3(256), 0, stream>>>(Wq, Wk, Wv, Wo, wqt, wkt, wvt, wot);
    gemm_mfma<0><<<dim3(32, 24), dim3(256), 0, stream>>>(
        xb, wqt, wkt, wvt, bq, bk, bv, qb, kb, vb);
    cvt_vt<<<dim3(32, 32), dim3(256), 0, stream>>>(vb, xb);   // xb := V^T
    if (split) {
        attn_mfma<1><<<dim3(2048), dim3(256), 0, stream>>>(qb, kb, xb, nullptr, pO, pML);
        attn_combine<<<dim3(1024), dim3(256), 0, stream>>>(pO, pML, cb);
    } else {
        attn_mfma<0><<<dim3(1024), dim3(256), 0, stream>>>(qb, kb, xb, cb, nullptr, nullptr);
    }
    gemm_mfma<1><<<dim3(32, 8), dim3(256), 0, stream>>>(
        cb, wot, nullptr, nullptr, bo, nullptr, nullptr, d_out, nullptr, nullptr);
}

// Round 9
// 186.910 us; speedup vs baseline: 1.8274x; 1.8274x over previous
//
#include <hip/hip_runtime.h>
#include <hip/hip_bf16.h>
#include <stdint.h>

#define DIM    1024
#define SEQ    2048
#define NB     2
#define NH     16
#define HD     64
#define NROWS  (NB*SEQ)   // 4096

typedef unsigned short u16;
typedef __attribute__((ext_vector_type(8))) short bf16x8;
typedef __attribute__((ext_vector_type(4))) float f32x4;
typedef __attribute__((ext_vector_type(4))) unsigned short u16x4;

#define NEG_INF (-__builtin_inff())

// float -> bf16 with round-to-nearest-even (cold paths)
__device__ __forceinline__ u16 f2bf(float f) {
    union { float f; uint32_t u; } x; x.f = f;
    uint32_t r = x.u + 0x7FFFu + ((x.u >> 16) & 1u);
    return (u16)(r >> 16);
}

// packed f32x2 -> bf16x2 (RNE on gfx950) — hot-path conversion
__device__ __forceinline__ uint32_t cvtpk(float a, float b) {
    uint32_t r;
    asm volatile("v_cvt_pk_bf16_f32 %0, %1, %2" : "=v"(r) : "v"(a), "v"(b));
    return r;
}

// async global->LDS, 16B per lane. LDS dest is wave-uniform base + lane*16.
__device__ __forceinline__ void gload_lds16(const void* g, void* l) {
    __builtin_amdgcn_global_load_lds(
        (const __attribute__((address_space(1))) void*)g,
        (__attribute__((address_space(3))) void*)l, 16, 0, 0);
}

// ---------------------------------------------------------------------------
// x (fp32 [4096][1024]) -> bf16. 4 elems/thread, exact cover.
// ---------------------------------------------------------------------------
__global__ __launch_bounds__(256)
void cvt_x(const float* __restrict__ in, u16* __restrict__ out)
{
    size_t i = (size_t)blockIdx.x * 256 + threadIdx.x;   // < 1048576
    float4 f = *(const float4*)&in[i * 4];
    u16x4 o = { f2bf(f.x), f2bf(f.y), f2bf(f.z), f2bf(f.w) };
    *(u16x4*)&out[i * 4] = o;
}

// ---------------------------------------------------------------------------
// W (fp32 [K=1024][N=1024]) -> Wt (bf16 [N][K]) — LDS-tiled 64x64 transpose.
// ---------------------------------------------------------------------------
__global__ __launch_bounds__(256)
void cvt_w(const float* __restrict__ Wq, const float* __restrict__ Wk,
           const float* __restrict__ Wv, const float* __restrict__ Wo,
           u16* __restrict__ Wqt, u16* __restrict__ Wkt,
           u16* __restrict__ Wvt, u16* __restrict__ Wot)
{
    __shared__ u16 Ws[64][68];
    const int z = blockIdx.z;
    const float* W = z == 0 ? Wq : z == 1 ? Wk : z == 2 ? Wv : Wo;
    u16* Wt        = z == 0 ? Wqt : z == 1 ? Wkt : z == 2 ? Wvt : Wot;
    const int k0 = blockIdx.x * 64;
    const int n0 = blockIdx.y * 64;
    const int tid = threadIdx.x;

    #pragma unroll
    for (int it = 0; it < 4; ++it) {
        int idx = tid + it * 256;
        int r = idx >> 4, cq = idx & 15;
        float4 f = *(const float4*)&W[(size_t)(k0 + r) * DIM + n0 + cq * 4];
        u16x4 o = { f2bf(f.x), f2bf(f.y), f2bf(f.z), f2bf(f.w) };
        *(u16x4*)&Ws[r][cq * 4] = o;
    }
    __syncthreads();
    #pragma unroll
    for (int it = 0; it < 4; ++it) {
        int idx = tid + it * 256;
        int rr = idx >> 4, cq = idx & 15;
        u16x4 o = { Ws[cq*4+0][rr], Ws[cq*4+1][rr], Ws[cq*4+2][rr], Ws[cq*4+3][rr] };
        *(u16x4*)&Wt[(size_t)(n0 + rr) * DIM + k0 + cq * 4] = o;
    }
}

// ---------------------------------------------------------------------------
// bf16 MFMA GEMM: C[M,N] = A[M,K] @ Wt^T + bias.  Tile 128 x BN, BK=64.
// MODE 0 (BN=128): fused QKV; Q output pre-scaled by 0.125*log2(e).
// MODE 1 (BN=64): O-projection, fp32 out; 512 blocks (2/CU) for latency
// hiding (the 128x128 variant gave only 256 blocks = 1 wave/SIMD).
// ---------------------------------------------------------------------------
template<int MODE, int BN>
__global__ __launch_bounds__(256)
void gemm_mfma(const u16* __restrict__ A,
               const u16* __restrict__ Wt0, const u16* __restrict__ Wt1,
               const u16* __restrict__ Wt2,
               const float* __restrict__ b0, const float* __restrict__ b1,
               const float* __restrict__ b2,
               void* __restrict__ o0, void* __restrict__ o1, void* __restrict__ o2)
{
    constexpr int NJ = BN / 32;            // B frags per wave per kk
    __shared__ __align__(16) uint8_t lds[16384 + BN * 128];
    uint8_t* Asb = lds;            // 128 rows x 128B (64 bf16), swizzled
    uint8_t* Bsb = lds + 16384;    // BN rows x 128B

    const int tid  = threadIdx.x;
    const int wid  = tid >> 6, lane = tid & 63;
    const int lr   = lane & 15, lg = lane >> 4;
    const int wr   = wid >> 1, wc = wid & 1;

    const int r0 = blockIdx.x * 128;
    const int c0 = blockIdx.y * BN;

    const u16* Wt; const float* bias; u16* obf = nullptr; float* ofp = nullptr;
    int cw; float qscale = 1.0f;
    if (MODE == 0) {
        int sel = c0 >> 10;              // 0..2 -> Q,K,V (128 | 1024)
        cw  = c0 & 1023;
        Wt   = sel == 0 ? Wt0 : sel == 1 ? Wt1 : Wt2;
        bias = sel == 0 ? b0  : sel == 1 ? b1  : b2;
        obf  = (u16*)(sel == 0 ? o0 : sel == 1 ? o1 : o2);
        if (sel == 0) qscale = 0.125f * 1.44269504088896f;   // 1/sqrt(64)*log2e
    } else {
        cw = c0; Wt = Wt0; bias = b0; ofp = (float*)o0;
    }

    f32x4 acc[4][NJ] = {};

    for (int k0 = 0; k0 < DIM; k0 += 64) {
        __syncthreads();   // previous compute done before overwrite
        #pragma unroll
        for (int seg = 0; seg < 4; ++seg) {
            int o   = seg * 4096 + tid * 16;        // linear LDS byte offset
            int row = o >> 7;                       // /128B per row
            int sch = ((o >> 4) & 7) ^ (row & 7);   // inverse-swizzled src chunk
            gload_lds16((const uint8_t*)A  + ((size_t)(r0 + row) << 11) + (k0 << 1) + (sch << 4),
                        Asb + seg * 4096 + (wid << 10) + (lane << 4));
            if (seg < BN / 32)
                gload_lds16((const uint8_t*)Wt + ((size_t)(cw + row) << 11) + (k0 << 1) + (sch << 4),
                            Bsb + seg * 4096 + (wid << 10) + (lane << 4));
        }
        __syncthreads();   // staging visible

        __builtin_amdgcn_s_setprio(1);
        #pragma unroll
        for (int kk = 0; kk < 2; ++kk) {
            bf16x8 a[4], b[NJ];
            #pragma unroll
            for (int i = 0; i < 4; ++i) {
                int ar = wr * 64 + i * 16 + lr;
                a[i] = *(const bf16x8*)(Asb + ar * 128 + ((((kk << 2) | lg) ^ (ar & 7)) << 4));
            }
            #pragma unroll
            for (int j = 0; j < NJ; ++j) {
                int br = wc * (BN / 2) + j * 16 + lr;
                b[j] = *(const bf16x8*)(Bsb + br * 128 + ((((kk << 2) | lg) ^ (br & 7)) << 4));
            }
            #pragma unroll
            for (int i = 0; i < 4; ++i)
                #pragma unroll
                for (int j = 0; j < NJ; ++j)
                    acc[i][j] = __builtin_amdgcn_mfma_f32_16x16x32_bf16(a[i], b[j], acc[i][j], 0, 0, 0);
        }
        __builtin_amdgcn_s_setprio(0);
    }

    // Epilogue. C/D layout: col = lane&15, row = (lane>>4)*4+reg.
    #pragma unroll
    for (int j = 0; j < NJ; ++j) {
        int colw = wc * (BN / 2) + j * 16 + lr;    // 0..BN-1 within tile
        float bv = bias[cw + colw];
        #pragma unroll
        for (int i = 0; i < 4; ++i) {
            #pragma unroll
            for (int r = 0; r < 4; ++r) {
                float val = (acc[i][j][r] + bv) * qscale;
                int row = r0 + wr * 64 + i * 16 + lg * 4 + r;
                if (MODE == 0) {
                    int col = cw + colw;           // 0..1023 within this W
                    int h = col >> 6, d = col & 63;
                    int bb = row >> 11, t = row & (SEQ - 1);
                    obf[((((size_t)bb * NH + h) * SEQ + t) << 6) + d] = f2bf(val);
                } else {
                    ofp[((size_t)row << 10) + c0 + colw] = val;
                }
            }
        }
    }
}

// ---------------------------------------------------------------------------
// Flash-style causal attention (R6 measured-best structure, reverted).
// Swapped-QK^T in-register softmax; T14 reg-staged K/V published to LDS;
// exp2-domain softmax with defer-max; P in-lane via cvt_pk.
// SPLIT=1: 2 kv-chunks per (bh,qt) + combine. SPLIT=0: single block.
// ---------------------------------------------------------------------------
template<int SPLIT>
__global__ __launch_bounds__(256)
void attn_mfma(const u16* __restrict__ q, const u16* __restrict__ k,
               const u16* __restrict__ v, u16* __restrict__ ctx,
               float* __restrict__ pO, float* __restrict__ pML)
{
    __shared__ __align__(16) uint8_t lds[16384];
    uint8_t* Ks = lds;              // [64 rows][128B]: LDS[r][c^(r&7)] = K[r][c]
    uint8_t* Vt = lds + 8192;       // [d][slot] swizzled (d^(d>>3))

    const int tid = threadIdx.x;
    const int wid = tid >> 6, lane = tid & 63;
    const int lr  = lane & 15, lg = lane >> 4;

    const int n = blockIdx.x;
    int bh, qt, k_lo, k_hi, pidx = 0;
    if (SPLIT) {
        bh = n & 31;
        int u = n >> 5;                  // 0..63
        qt = u >> 1;
        int chunk = u & 1;
        int T = qt + 1, hh = (T + 1) >> 1;
        k_lo = chunk ? hh : 0;
        k_hi = chunk ? T : hh;
        pidx = (((bh << 5) | qt) << 1) | chunk;
    } else {
        int j4 = n >> 8, c = n & 255, ch = c >> 5;
        bh = c & 31;
        qt = (j4 == 0) ? ch : (j4 == 1) ? (15 - ch)
           : (j4 == 2) ? (16 + ch) : (31 - ch);
        k_lo = 0; k_hi = qt + 1;
    }

    const size_t hb = (size_t)bh * SEQ * HD;
    const int q0 = qt * 64;

    // Q fragments: direct global->reg (row = q0 + wid*16 + lr)
    const u16* qrow = q + hb + ((size_t)(q0 + wid * 16 + lr) << 6);
    bf16x8 aQ0 = *(const bf16x8*)(qrow + lg * 8);
    bf16x8 aQ1 = *(const bf16x8*)(qrow + 32 + lg * 8);

    // K staging geometry: thread -> row kr, even chunk pair kc0
    const int kr  = tid >> 2;
    const int kc0 = (tid & 3) * 2;
    const u16* kbase = k + hb + ((size_t)kr << 6) + kc0 * 8;

    // V staging geometry: kv-pair vp, d-group vg
    const int vp = tid >> 3;
    const int vg = tid & 7;
    const int vj  = vp >> 3;               // (2vp)>>4
    const int vlg = (vp >> 1) & 3;         // ((2vp)>>2)&3
    const int vrr = (vp & 1) * 2;          // (2vp)&3
    const int vslot = (vj & 1) * 32 + vlg * 8 + ((vj >> 1) << 2) + vrr;  // even
    const u16* vbase = v + hb + ((size_t)(2 * vp) << 6) + vg * 8;

    // T14 prefetch: K,V regs for tile k_lo
    bf16x8 kpre0 = {}, kpre1 = {}, vpre0 = {}, vpre1 = {};
    if (k_lo < k_hi) {
        const u16* ks = kbase + ((size_t)k_lo << 12);
        kpre0 = *(const bf16x8*)(ks);
        kpre1 = *(const bf16x8*)(ks + 8);
        const u16* vs = vbase + ((size_t)k_lo << 12);
        vpre0 = *(const bf16x8*)(vs);
        vpre1 = *(const bf16x8*)(vs + 64);
    }

    f32x4 acc[4] = {};
    float m_own = NEG_INF;   // running max (log2-domain) for q-row wid*16+lr
    float l_own = 0.f;

    for (int kt = k_lo; kt < k_hi; ++kt) {
        __syncthreads();   // prev iter done reading Ks/Vt
        // publish K tile from regs (swizzled chunks)
        *(bf16x8*)(Ks + kr * 128 + ((kc0       ^ (kr & 7)) << 4)) = kpre0;
        *(bf16x8*)(Ks + kr * 128 + (((kc0 + 1) ^ (kr & 7)) << 4)) = kpre1;
        // publish V tile from regs (permuted slots, u32 kv-pairs, swizzled)
        #pragma unroll
        for (int i = 0; i < 8; ++i) {
            int d = vg * 8 + i;
            int swzd = (d ^ (d >> 3)) & 7;
            uint32_t w = (uint32_t)(u16)vpre0[i] | ((uint32_t)(u16)vpre1[i] << 16);
            *(uint32_t*)(Vt + d * 128 + ((((vslot >> 3) ^ swzd) << 4))
                         + ((vslot & 7) << 1)) = w;
        }
        __syncthreads();

        // T14: issue NEXT tile's K,V global loads; latency hides under compute
        if (kt + 1 < k_hi) {
            const u16* ks = kbase + ((size_t)(kt + 1) << 12);
            kpre0 = *(const bf16x8*)(ks);
            kpre1 = *(const bf16x8*)(ks + 8);
            const u16* vs = vbase + ((size_t)(kt + 1) << 12);
            vpre0 = *(const bf16x8*)(vs);
            vpre1 = *(const bf16x8*)(vs + 64);
        }

        // S^T = K·Q : A = K fragment, B = Q fragment (swapped operands)
        f32x4 s[4];
        __builtin_amdgcn_s_setprio(1);
        #pragma unroll
        for (int j = 0; j < 4; ++j) {
            int krow = j * 16 + lr;
            bf16x8 b0 = *(const bf16x8*)(Ks + krow * 128 + ((lg       ^ (krow & 7)) << 4));
            bf16x8 b1 = *(const bf16x8*)(Ks + krow * 128 + (((4 | lg) ^ (krow & 7)) << 4));
            f32x4 z = {0.f, 0.f, 0.f, 0.f};
            z    = __builtin_amdgcn_mfma_f32_16x16x32_bf16(b0, aQ0, z, 0, 0, 0);
            s[j] = __builtin_amdgcn_mfma_f32_16x16x32_bf16(b1, aQ1, z, 0, 0, 0);
        }
        __builtin_amdgcn_s_setprio(0);

        if (kt == qt) {                  // causal mask (tile-relative)
            #pragma unroll
            for (int j = 0; j < 4; ++j)
                #pragma unroll
                for (int r = 0; r < 4; ++r)
                    if (j * 16 + lg * 4 + r > wid * 16 + lr) s[j][r] = NEG_INF;
        }

        // softmax over this lane's 16 kv values (log2 domain)
        float rm = NEG_INF;
        #pragma unroll
        for (int j = 0; j < 4; ++j) {
            float a = fmaxf(fmaxf(s[j][0], s[j][1]), fmaxf(s[j][2], s[j][3]));
            rm = fmaxf(rm, a);
        }
        rm = fmaxf(rm, __shfl_xor(rm, 16));
        rm = fmaxf(rm, __shfl_xor(rm, 32));

        // defer-max: only rescale when the max actually grew (P <= 2^8)
        if (!__all(rm <= m_own + 8.f)) {
            float mnew = fmaxf(m_own, rm);
            float aown = exp2f(m_own - mnew);   // first tile: exp2(-inf)=0
            m_own = mnew;
            l_own *= aown;
            float ar[4];
            #pragma unroll
            for (int r = 0; r < 4; ++r) ar[r] = __shfl(aown, lg * 4 + r);
            #pragma unroll
            for (int ni = 0; ni < 4; ++ni)
                #pragma unroll
                for (int r = 0; r < 4; ++r)
                    acc[ni][r] *= ar[r];
        }

        float rs = 0.f;
        #pragma unroll
        for (int j = 0; j < 4; ++j)
            #pragma unroll
            for (int r = 0; r < 4; ++r) {
                float p = exp2f(s[j][r] - m_own);
                s[j][r] = p;
                rs += p;
            }
        rs += __shfl_xor(rs, 16);
        rs += __shfl_xor(rs, 32);
        l_own += rs;

        // P A-fragments via packed cvt: pa0 = {s0[0..3], s2[0..3]}, pa1 = {s1,s3}
        union { uint32_t u[4]; bf16x8 h; } P0, P1;
        P0.u[0] = cvtpk(s[0][0], s[0][1]); P0.u[1] = cvtpk(s[0][2], s[0][3]);
        P0.u[2] = cvtpk(s[2][0], s[2][1]); P0.u[3] = cvtpk(s[2][2], s[2][3]);
        P1.u[0] = cvtpk(s[1][0], s[1][1]); P1.u[1] = cvtpk(s[1][2], s[1][3]);
        P1.u[2] = cvtpk(s[3][0], s[3][1]); P1.u[3] = cvtpk(s[3][2], s[3][3]);

        // O += P @ V   (B = V from permuted slots; chunks st*4+lg)
        __builtin_amdgcn_s_setprio(1);
        #pragma unroll
        for (int ni = 0; ni < 4; ++ni) {
            int vrow = ni * 16 + lr;
            int swzd = (vrow ^ (vrow >> 3)) & 7;
            bf16x8 vb0 = *(const bf16x8*)(Vt + vrow * 128 + ((lg       ^ swzd) << 4));
            bf16x8 vb1 = *(const bf16x8*)(Vt + vrow * 128 + (((4 | lg) ^ swzd) << 4));
            acc[ni] = __builtin_amdgcn_mfma_f32_16x16x32_bf16(P0.h, vb0, acc[ni], 0, 0, 0);
            acc[ni] = __builtin_amdgcn_mfma_f32_16x16x32_bf16(P1.h, vb1, acc[ni], 0, 0, 0);
        }
        __builtin_amdgcn_s_setprio(0);
    }

    if (SPLIT) {
        // partial O (unnormalized fp32) + (m,l)
        float* Op = pO + (size_t)pidx * 4096;
        #pragma unroll
        for (int r = 0; r < 4; ++r) {
            int row = wid * 16 + lg * 4 + r;
            #pragma unroll
            for (int ni = 0; ni < 4; ++ni)
                Op[row * 64 + ni * 16 + lr] = acc[ni][r];
        }
        if (lg == 0) {   // lanes 0..15 hold rows wid*16+lr
            pML[pidx * 128 + wid * 16 + lr]      = m_own;
            pML[pidx * 128 + 64 + wid * 16 + lr] = l_own;
        }
    } else {
        float rinv = 1.f / l_own;
        float rl[4];
        #pragma unroll
        for (int r = 0; r < 4; ++r) rl[r] = __shfl(rinv, lg * 4 + r);
        const int b = bh >> 4, h = bh & 15;
        #pragma unroll
        for (int r = 0; r < 4; ++r) {
            int t = q0 + wid * 16 + lg * 4 + r;
            size_t base = (((size_t)b * SEQ + t) << 10) + (h << 6);
            #pragma unroll
            for (int ni = 0; ni < 4; ++ni)
                ctx[base + ni * 16 + lr] = f2bf(acc[ni][r] * rl[r]);
        }
    }
}

// ---------------------------------------------------------------------------
// Merge the 2 kv-chunk partials: O = (O0*2^(m0-m) + O1*2^(m1-m)) / l.
// One thread per (q-row, 16-d segment): 262144 threads.
// ---------------------------------------------------------------------------
__global__ __launch_bounds__(256)
void attn_combine(const float* __restrict__ pO, const float* __restrict__ pML,
                  u16* __restrict__ ctx)
{
    int gid  = blockIdx.x * 256 + threadIdx.x;   // < 262144
    int rg   = gid >> 2;                         // global q-row 0..65535
    int dseg = gid & 3;
    int bh = rg >> 11;
    int qt = (rg >> 6) & 31;
    int r  = rg & 63;
    int p0 = ((bh << 5) | qt) << 1;

    float m0 = pML[p0 * 128 + r],       l0 = pML[p0 * 128 + 64 + r];
    float m1 = pML[(p0 + 1) * 128 + r], l1 = pML[(p0 + 1) * 128 + 64 + r];
    float m  = fmaxf(m0, m1);
    float s0 = exp2f(m0 - m), s1 = exp2f(m1 - m);
    float rl = 1.f / (l0 * s0 + l1 * s1);

    const float* O0 = pO + (size_t)p0 * 4096 + r * 64 + dseg * 16;
    const float* O1 = O0 + 4096;

    int b = bh >> 4, h = bh & 15, t = qt * 64 + r;
    u16* dst = ctx + (((size_t)b * SEQ + t) << 10) + (h << 6) + dseg * 16;

    u16x4 o[4];
    #pragma unroll
    for (int i = 0; i < 4; ++i) {
        float4 a = *(const float4*)&O0[i * 4];
        float4 c = *(const float4*)&O1[i * 4];
        o[i].x = f2bf((a.x * s0 + c.x * s1) * rl);
        o[i].y = f2bf((a.y * s0 + c.y * s1) * rl);
        o[i].z = f2bf((a.z * s0 + c.z * s1) * rl);
        o[i].w = f2bf((a.w * s0 + c.w * s1) * rl);
    }
    *(u16x4*)(dst)      = o[0];
    *(u16x4*)(dst + 4)  = o[1];
    *(u16x4*)(dst + 8)  = o[2];
    *(u16x4*)(dst + 12) = o[3];
}

// ---------------------------------------------------------------------------
extern "C" void kernel_launch(void* const* d_in, const int* in_sizes, int n_in,
                              void* d_out, int out_size, void* d_ws, size_t ws_size,
                              hipStream_t stream)
{
    (void)in_sizes; (void)n_in; (void)out_size;
    const float* x  = (const float*)d_in[0];
    const float* Wq = (const float*)d_in[1];
    const float* bq = (const float*)d_in[2];
    const float* Wk = (const float*)d_in[3];
    const float* bk = (const float*)d_in[4];
    const float* Wv = (const float*)d_in[5];
    const float* bv = (const float*)d_in[6];
    const float* Wo = (const float*)d_in[7];
    const float* bo = (const float*)d_in[8];

    u16* ws = (u16*)d_ws;
    const size_t M1 = (size_t)1024 * 1024;     // 1M elems
    const size_t M4 = (size_t)NROWS * DIM;     // 4M elems
    u16* xb  = ws;                 // x as bf16                     (8 MB)
    u16* wqt = ws + M4;            // W^T bf16 [n][k]               (2 MB each)
    u16* wkt = wqt + M1;
    u16* wvt = wkt + M1;
    u16* wot = wvt + M1;
    u16* qb  = wot + M1;           // q/k/v bf16 [B,H,T,D]          (8 MB each)
    u16* kb  = qb + M4;
    u16* vb  = kb + M4;
    u16* cb  = vb + M4;            // ctx bf16 [B,T,C]              (8 MB)
    float* pO  = (float*)(cb + M4);            // 2048 x 4096 fp32  (33.5 MB)
    float* pML = pO + (size_t)2048 * 4096;     // 2048 x 128  fp32  (1 MB)

    const size_t need = (size_t)(cb + M4 - ws) * 2      // 48 MB in bytes
                      + (size_t)2048 * 4096 * 4 + (size_t)2048 * 128 * 4;
    const bool split = ws_size >= need;

    cvt_x<<<dim3(4096), dim3(256), 0, stream>>>(x, xb);
    cvt_w<<<dim3(16, 16, 4), dim3(256), 0, stream>>>(Wq, Wk, Wv, Wo, wqt, wkt, wvt, wot);
    gemm_mfma<0, 128><<<dim3(32, 24), dim3(256), 0, stream>>>(
        xb, wqt, wkt, wvt, bq, bk, bv, qb, kb, vb);
    if (split) {
        attn_mfma<1><<<dim3(2048), dim3(256), 0, stream>>>(qb, kb, vb, nullptr, pO, pML);
        attn_combine<<<dim3(1024), dim3(256), 0, stream>>>(pO, pML, cb);
    } else {
        attn_mfma<0><<<dim3(1024), dim3(256), 0, stream>>>(qb, kb, vb, cb, nullptr, nullptr);
    }
    gemm_mfma<1, 64><<<dim3(32, 16), dim3(256), 0, stream>>>(
        cb, wot, nullptr, nullptr, bo, nullptr, nullptr, d_out, nullptr, nullptr);
}